// Round 4
// baseline (9177.965 us; speedup 1.0000x reference)
//
#include <hip/hip_runtime.h>
#include <hip/hip_bf16.h>

// ============================================================================
// WindowAttention round 3: identical audited body to round 2, but output is
// written as FLOAT32 (the reference's output dtype, per harness convention
// "else float*"). Round-2 forensics: finite absmax 3.898 > max|ref| matches
// bf16-written-but-f32-read garbage; input f32 theory already confirmed by
// NaN disappearing in round 2.
//
// Runtime input-dtype detector retained (4 bytes of ws): selects f32 vs bf16
// read path for all 7 inputs (expected: f32).
// LDS 146,944 B -> 1 block/CU (correctness first; perf work next round).
// ============================================================================

typedef unsigned short u16;
typedef unsigned int   u32;

#define NTOK 128
#define CDIM 180
#define NHEAD 6
#define XSTR 182            // f32 x stride
#define KVSTR 36            // f32 k/v stride (rows 144 B, float4-aligned)
#define SLSTR 33            // f32 slab stride
#define QKSCALE 0.18257418583505536f   // 30^-0.5

__device__ __forceinline__ float bflo(u32 u){ return __uint_as_float(u << 16); }
__device__ __forceinline__ float bfhi(u32 u){ return __uint_as_float(u & 0xFFFF0000u); }
__device__ __forceinline__ float bf2f(u16 v){ return __uint_as_float(((u32)v) << 16); }

// dtype-templated input loaders. F32=true: inputs are float32.
template<bool F32> __device__ __forceinline__ float ld1(const void* p, size_t i) {
  if constexpr (F32) return reinterpret_cast<const float*>(p)[i];
  else               return bf2f(reinterpret_cast<const u16*>(p)[i]);
}
template<bool F32> __device__ __forceinline__ float2 ld2(const void* p, size_t i) {
  if constexpr (F32) return *reinterpret_cast<const float2*>(reinterpret_cast<const float*>(p) + i);
  else {
    u32 r = *reinterpret_cast<const u32*>(reinterpret_cast<const u16*>(p) + i);
    return float2{bflo(r), bfhi(r)};
  }
}
template<bool F32> __device__ __forceinline__ float4 ld4(const void* p, size_t i) {
  if constexpr (F32) return *reinterpret_cast<const float4*>(reinterpret_cast<const float*>(p) + i);
  else {
    uint2 r = *reinterpret_cast<const uint2*>(reinterpret_cast<const u16*>(p) + i);
    return float4{bflo(r.x), bfhi(r.x), bflo(r.y), bfhi(r.y)};
  }
}

// ---------------------------------------------------------------------------
// dtype detector: low-u16 bf16-exponent band test on first 4096 words of x.
// f32 gaussian -> ~22% in band; packed bf16 gaussian -> ~100%. flag=1 => bf16.
// ---------------------------------------------------------------------------
__global__ void detect_dtype(const u32* __restrict__ xw, int* __restrict__ flag) {
  __shared__ int cnt[256];
  int c = 0;
  for (int i = threadIdx.x; i < 4096; i += 256) {
    u32 e = (xw[i] >> 7) & 0xFF;
    c += (e >= 0x58 && e <= 0x90) ? 1 : 0;
  }
  cnt[threadIdx.x] = c;
  __syncthreads();
  if (threadIdx.x == 0) {
    int t = 0;
    for (int i = 0; i < 256; ++i) t += cnt[i];
    flag[0] = (t >= 2458) ? 1 : 0;     // 60% vote threshold
  }
}

// ---------------------------------------------------------------------------
// fused per-window body, templated on input dtype
// ---------------------------------------------------------------------------
template<bool F32>
__device__ void body(const void* __restrict__ x,    // (1024,128,180)
                     const void* __restrict__ mask, // (64,128,128)
                     const void* __restrict__ rpb,  // (675,6)
                     const void* __restrict__ Wqs,  // (540,180)
                     const void* __restrict__ Wqm,  // (540,180)
                     const void* __restrict__ Wp,   // (180,360)
                     const void* __restrict__ bp,   // (180)
                     float* __restrict__ out,       // (1024,128,180) f32
                     float* x_s, float* k_s, float* v_s, float* slab)
{
  const int tid = threadIdx.x;
  const int b   = blockIdx.x;
  const int n   = tid >> 1;      // token (qkv row / attention query)
  const int hi  = tid & 1;       // partner half; partner lane = tid^1
  const int db  = hi * 15;       // qkv dim sub-range
  const int w64 = b & 63;

  // projection ownership: 2 tokens x 45 out-cols, acc in registers
  const int rp = (tid & 63) * 2;
  const int og = tid >> 6;       // wave-uniform
  float acc0[45], acc1[45];
  #pragma unroll
  for (int o2 = 0; o2 < 45; ++o2) { acc0[o2] = 0.f; acc1[o2] = 0.f; }

  // bias i-coords for self attention (query n)
  const int bi_d = n >> 6, bi_h = (n >> 3) & 7, bi_w = n & 7;

  // ---- stage x window into LDS (f32, exact) ----
  {
    const size_t xbase = (size_t)b * (NTOK * CDIM);
    for (int i = tid * 4; i < NTOK * CDIM; i += 1024) {
      float4 f = ld4<F32>(x, xbase + i);
      int r = i / CDIM, c = i - r * CDIM;     // c stays multiple of 4
      float* dst = &x_s[r * XSTR + c];
      dst[0] = f.x; dst[1] = f.y; dst[2] = f.z; dst[3] = f.w;
    }
  }

  for (int pass = 0; pass < 2; ++pass) {
    const bool self = (pass == 0);
    const void* W = self ? Wqs : Wqm;
    if (!self) {
      __syncthreads();
      // x += sine position encoding, computed on the fly (f32, no rounding)
      for (int i = tid; i < NTOK * CDIM; i += 256) {
        int r = i / CDIM, c = i - r * CDIM;
        int n64 = r & 63;
        int t = (c < 90) ? c : (c - 90);
        float e = (c < 90) ? (float)((n64 >> 3) + 1) : (float)((n64 & 7) + 1);
        float embed = e * 0.78539807f;                 // 2*pi / 8.000001
        float expo  = (float)(t & ~1) * (1.0f / 90.0f);
        float arg   = embed * exp2f(-13.2877124f * expo);  // 10000^-expo
        float pbv   = (t & 1) ? cosf(arg) : sinf(arg);
        x_s[r * XSTR + c] += pbv;
      }
    }
    for (int h = 0; h < NHEAD; ++h) {
      __syncthreads();
      // ---------- qkv: thread (n,hi) computes dims [db, db+15) ----------
      float qfull[32];
      {
        float aq[15], ak[15], av[15];
        #pragma unroll
        for (int d = 0; d < 15; ++d) { aq[d] = 0.f; ak[d] = 0.f; av[d] = 0.f; }
        const float* xr = &x_s[n * XSTR];
        const size_t wq0 = (size_t)(0 * CDIM + h * 30 + db) * CDIM;
        const size_t wk0 = (size_t)(1 * CDIM + h * 30 + db) * CDIM;
        const size_t wv0 = (size_t)(2 * CDIM + h * 30 + db) * CDIM;
        for (int c = 0; c < CDIM; c += 4) {
          float2 xa = *reinterpret_cast<const float2*>(xr + c);
          float2 xb = *reinterpret_cast<const float2*>(xr + c + 2);
          #pragma unroll
          for (int d = 0; d < 15; ++d) {
            float4 a = ld4<F32>(W, wq0 + (size_t)d * CDIM + c);
            aq[d] = fmaf(xa.x, a.x, fmaf(xa.y, a.y, fmaf(xb.x, a.z, fmaf(xb.y, a.w, aq[d]))));
            float4 bk = ld4<F32>(W, wk0 + (size_t)d * CDIM + c);
            ak[d] = fmaf(xa.x, bk.x, fmaf(xa.y, bk.y, fmaf(xb.x, bk.z, fmaf(xb.y, bk.w, ak[d]))));
            float4 bv = ld4<F32>(W, wv0 + (size_t)d * CDIM + c);
            av[d] = fmaf(xa.x, bv.x, fmaf(xa.y, bv.y, fmaf(xb.x, bv.z, fmaf(xb.y, bv.w, av[d]))));
          }
        }
        float* krow = &k_s[n * KVSTR];
        float* vrow = &v_s[n * KVSTR];
        #pragma unroll
        for (int d = 0; d < 15; ++d) {
          float qv = aq[d] * QKSCALE;
          float pq = __shfl_xor(qv, 1);
          qfull[d]      = hi ? pq : qv;      // compile-time indices only
          qfull[15 + d] = hi ? qv : pq;
          krow[db + d] = ak[d];
          vrow[db + d] = av[d];
        }
        qfull[30] = 0.f; qfull[31] = 0.f;
        if (hi) { krow[30] = 0.f; krow[31] = 0.f; vrow[30] = 0.f; vrow[31] = 0.f; }
      }
      __syncthreads();
      // ---------- attention: query n, key-range split by hi ----------
      float o[32];
      #pragma unroll
      for (int d = 0; d < 32; ++d) o[d] = 0.f;
      float m = -1e30f, l = 0.f;

      int jbeg, jcount, kbase;
      if (self) { jbeg = hi * 64; jcount = 64; kbase = 0; }
      else      { jbeg = hi * 32; jcount = 32; kbase = (n < 64) ? 64 : 0; }
      const int il = self ? n : (n & 63);
      const size_t mbase = (size_t)w64 * (NTOK * NTOK) + (size_t)il * NTOK;

      for (int jj = 0; jj < jcount; jj += 4) {
        const int jl = jbeg + jj;
        const int jg = kbase + jl;
        float s[4];
        #pragma unroll
        for (int u = 0; u < 4; ++u) {
          const float* kr = &k_s[(jg + u) * KVSTR];
          float t0 = 0.f, t1 = 0.f, t2 = 0.f, t3 = 0.f;
          #pragma unroll
          for (int kk = 0; kk < 8; ++kk) {
            float4 kv = *reinterpret_cast<const float4*>(kr + 4 * kk);
            t0 = fmaf(qfull[4 * kk],     kv.x, t0);
            t1 = fmaf(qfull[4 * kk + 1], kv.y, t1);
            t2 = fmaf(qfull[4 * kk + 2], kv.z, t2);
            t3 = fmaf(qfull[4 * kk + 3], kv.w, t3);
          }
          float sv = (t0 + t1) + (t2 + t3);
          sv += ld1<F32>(mask, mbase + (size_t)(jl + u));
          if (self) {
            const int j = jl + u;
            const int dj = j >> 6, hj = (j >> 3) & 7, wj = j & 7;
            const int idx = (bi_d - dj + 1) * 225 + (bi_h - hj + 7) * 15 + (bi_w - wj + 7);
            sv += ld1<F32>(rpb, (size_t)idx * 6 + h);
          }
          s[u] = sv;
        }
        float M = fmaxf(fmaxf(fmaxf(s[0], s[1]), fmaxf(s[2], s[3])), m);
        float corr = __expf(m - M);
        float p0 = __expf(s[0] - M), p1 = __expf(s[1] - M);
        float p2 = __expf(s[2] - M), p3 = __expf(s[3] - M);
        l = l * corr + ((p0 + p1) + (p2 + p3));
        const float* v0 = &v_s[jg * KVSTR];
        const float* v1 = v0 + KVSTR;
        const float* v2 = v1 + KVSTR;
        const float* v3 = v2 + KVSTR;
        #pragma unroll
        for (int kk = 0; kk < 8; ++kk) {
          float4 a0 = *reinterpret_cast<const float4*>(v0 + 4 * kk);
          float4 a1 = *reinterpret_cast<const float4*>(v1 + 4 * kk);
          float4 a2 = *reinterpret_cast<const float4*>(v2 + 4 * kk);
          float4 a3 = *reinterpret_cast<const float4*>(v3 + 4 * kk);
          o[4*kk]   = fmaf(o[4*kk],   corr, fmaf(p0, a0.x, fmaf(p1, a1.x, fmaf(p2, a2.x, p3 * a3.x))));
          o[4*kk+1] = fmaf(o[4*kk+1], corr, fmaf(p0, a0.y, fmaf(p1, a1.y, fmaf(p2, a2.y, p3 * a3.y))));
          o[4*kk+2] = fmaf(o[4*kk+2], corr, fmaf(p0, a0.z, fmaf(p1, a1.z, fmaf(p2, a2.z, p3 * a3.z))));
          o[4*kk+3] = fmaf(o[4*kk+3], corr, fmaf(p0, a0.w, fmaf(p1, a1.w, fmaf(p2, a2.w, p3 * a3.w))));
        }
        m = M;
      }
      // ---------- merge partner halves (shuffles); write head-slab ----------
      {
        float m2 = __shfl_xor(m, 1);
        float l2 = __shfl_xor(l, 1);
        float M  = fmaxf(m, m2);
        float e1 = __expf(m - M);
        float e2 = __expf(m2 - M);
        float L  = l * e1 + l2 * e2;
        float inv = 1.0f / L;
        const int r = self ? n : ((n + 64) & 127);   // mutual swaps halves
        float* srow = &slab[r * SLSTR];
        #pragma unroll
        for (int d = 0; d < 30; ++d) {
          float o2v = __shfl_xor(o[d], 1);
          float xo = (o[d] * e1 + o2v * e2) * inv;
          if ((d < 15) == (hi == 0)) srow[d] = xo;   // each lane writes its half
        }
      }
      __syncthreads();
      // ---------- projection accumulate: slab @ Wp[:, cb:cb+30) ----------
      {
        const int cb = self ? (CDIM + h * 30) : (h * 30);
        float s0[30], s1[30];
        #pragma unroll
        for (int d = 0; d < 30; ++d) {
          s0[d] = slab[rp * SLSTR + d];
          s1[d] = slab[(rp + 1) * SLSTR + d];
        }
        const size_t wrow = (size_t)(og * 45) * 360 + cb;
        #pragma unroll
        for (int o2 = 0; o2 < 45; ++o2) {
          const size_t wr = wrow + (size_t)o2 * 360;
          float t0 = 0.f, t1 = 0.f;
          #pragma unroll
          for (int d = 0; d < 30; d += 2) {
            float2 w2 = ld2<F32>(Wp, wr + d);
            t0 = fmaf(s0[d], w2.x, fmaf(s0[d + 1], w2.y, t0));
            t1 = fmaf(s1[d], w2.x, fmaf(s1[d + 1], w2.y, t1));
          }
          acc0[o2] += t0;
          acc1[o2] += t1;
        }
      }
    } // heads
  } // passes

  // ---- epilogue: + b_proj, write FLOAT32 ----
  {
    float* o0 = out + ((size_t)b * NTOK + rp) * CDIM + og * 45;
    float* o1 = o0 + CDIM;
    #pragma unroll
    for (int o2 = 0; o2 < 45; ++o2) {
      float bb = ld1<F32>(bp, og * 45 + o2);
      o0[o2] = acc0[o2] + bb;
      o1[o2] = acc1[o2] + bb;
    }
  }
}

__global__ __launch_bounds__(256, 1) void fused_all(
    const void* __restrict__ x,    const void* __restrict__ mask,
    const void* __restrict__ rpb,  const void* __restrict__ Wqs,
    const void* __restrict__ Wqm,  const void* __restrict__ Wp,
    const void* __restrict__ bp,   const int* __restrict__ flag,
    float* __restrict__ out)
{
  __shared__ __align__(16) float x_s[NTOK * XSTR];    // 93,184 B
  __shared__ __align__(16) float k_s[NTOK * KVSTR];   // 18,432 B
  __shared__ __align__(16) float v_s[NTOK * KVSTR];   // 18,432 B
  __shared__ __align__(16) float slab[NTOK * SLSTR];  // 16,896 B -> 146,944 B
  if (flag[0]) body<false>(x, mask, rpb, Wqs, Wqm, Wp, bp, out, x_s, k_s, v_s, slab);
  else         body<true >(x, mask, rpb, Wqs, Wqm, Wp, bp, out, x_s, k_s, v_s, slab);
}

// ---------------------------------------------------------------------------
extern "C" void kernel_launch(void* const* d_in, const int* in_sizes, int n_in,
                              void* d_out, int out_size, void* d_ws, size_t ws_size,
                              hipStream_t stream) {
  int* flag = (int*)d_ws;   // 4 bytes of ws -- the only scratch used
  detect_dtype<<<1, 256, 0, stream>>>((const u32*)d_in[0], flag);
  fused_all<<<1024, 256, 0, stream>>>(d_in[0], d_in[1], d_in[2], d_in[3],
                                      d_in[4], d_in[5], d_in[6], flag,
                                      (float*)d_out);
}